// Round 9
// baseline (354.746 us; speedup 1.0000x reference)
//
#include <hip/hip_runtime.h>
#include <stdint.h>

// ---------- types ----------
typedef __bf16 bf16x8 __attribute__((ext_vector_type(8)));
typedef __bf16 bf16x2 __attribute__((ext_vector_type(2)));
typedef float  f32x4  __attribute__((ext_vector_type(4)));
typedef unsigned short u16x4 __attribute__((ext_vector_type(4)));
typedef unsigned short u16x8 __attribute__((ext_vector_type(8)));

#define DEVI __device__ __forceinline__

// problem constants
constexpr int Bc = 4, Hc = 16, Ss = 2048, Dd = 128;
constexpr int BH = Bc * Hc;          // 64 heads
constexpr int BM = 256;              // q-rows per workgroup (4 waves x 64), mt=4 reuse
constexpr int MT = 4;                // 16-row fragments per wave
constexpr int BN = 32;               // keys per K-tile
constexpr int NTIL = Ss / BN;        // 64 tiles
// scale folds in log2(e): e^(qk/128) = 2^((qk*log2e)/128)
constexpr float SCALE = 1.44269504088896340736f / 128.0f;

constexpr int TILE_B = BN * Dd * 2;  // 8192 B (one K tile; V tile same)
constexpr int SET_B  = 2 * TILE_B;   // 16384 B per buffer set {K, V}
constexpr int NSET   = 3;            // triple-buffer: compute t, t+1 landed/landing, t+2 in flight
constexpr int LDS_BYTES = NSET * SET_B;   // 49152 B -> 2 WGs/CU (grid = 2/CU exact)

DEVI unsigned short f2bf_bits(float x) {
  unsigned u = __builtin_bit_cast(unsigned, x);
  u += 0x7fffu + ((u >> 16) & 1u);          // round-to-nearest-even
  return (unsigned short)(u >> 16);
}
DEVI __bf16 f2bf(float x) {
  unsigned short b = f2bf_bits(x);
  return __builtin_bit_cast(__bf16, b);
}
// pack two fp32 -> dword of 2 bf16 (compiler emits v_cvt_pk_bf16_f32)
DEVI unsigned pk2(float a, float b) {
  bf16x2 t; t[0] = (__bf16)a; t[1] = (__bf16)b;
  return __builtin_bit_cast(unsigned, t);
}

// hardware 2^x (v_exp_f32)
DEVI float exp2_hw(float x) { return __builtin_amdgcn_exp2f(x); }

// async global->LDS, 16B per lane; LDS dest = wave-uniform base + lane*16
DEVI void gload_lds16(const void* g, void* l) {
  __builtin_amdgcn_global_load_lds(
      (const __attribute__((address_space(1))) unsigned*)(uintptr_t)g,
      (__attribute__((address_space(3))) unsigned*)(unsigned)(uintptr_t)l,
      16, 0, 0);
}

// ---------------- fused pre-pass (unchanged, measured-good) ----------------
constexpr int LDT2 = 136;
__global__ void k_prep(const float* __restrict__ kin, __bf16* __restrict__ kout,
                       const float* __restrict__ v, __bf16* __restrict__ vt) {
  __shared__ __align__(16) unsigned short tile[64 * LDT2];
  const int bx = blockIdx.x;
  const int u = threadIdx.x;
  if (bx >= 2048) {
    constexpr int N4 = (BH * Ss * Dd) / 4;
    int i = (bx - 2048) * 256 + u;
    const int stride = 2048 * 256;
    #pragma unroll
    for (int it = 0; it < N4 / (2048 * 256); it++, i += stride) {
      float4 x = ((const float4*)kin)[i];
      ushort4 o;
      o.x = f2bf_bits(x.x); o.y = f2bf_bits(x.y);
      o.z = f2bf_bits(x.z); o.w = f2bf_bits(x.w);
      ((ushort4*)kout)[i] = o;
    }
    return;
  }
  const int bh = bx >> 5;
  const int s0 = (bx & 31) * 64;
  const float4* src = (const float4*)(v + ((size_t)bh * Ss + s0) * Dd);
  #pragma unroll
  for (int i = 0; i < 8; i++) {
    int f = i * 256 + u;
    int row = f >> 5;
    int c4 = (f & 31) << 2;
    float4 x = src[f];
    u16x4 o;
    o[0] = f2bf_bits(x.x); o[1] = f2bf_bits(x.y);
    o[2] = f2bf_bits(x.z); o[3] = f2bf_bits(x.w);
    *(u16x4*)&tile[row * LDT2 + c4] = o;
  }
  __syncthreads();
  const int so = u & 7;
  const int dq = u >> 3;
  u16x4 tin[8];
  #pragma unroll
  for (int i = 0; i < 8; i++)
    tin[i] = *(const u16x4*)&tile[(so * 8 + i) * LDT2 + dq * 4];
  #pragma unroll
  for (int j = 0; j < 4; j++) {
    u16x8 o;
    #pragma unroll
    for (int i = 0; i < 8; i++) o[i] = tin[i][j];
    *(u16x8*)(vt + ((size_t)bh * Dd + dq * 4 + j) * Ss + s0 + so * 8) = o;
  }
}

// ---------------- flash attention ----------------
// grid: 512 = 8 q-tiles x 64 heads. R7 base (4 waves, mt=4, in-register
// softmax via key-permuted K staging) + counted-vmcnt triple-buffer pipeline:
// body t stages tile t+2, then computes tile t, then waits vmcnt(4) -- only
// tile (t+1)'s 4 loads are drained; (t+2)'s stay in flight ACROSS the raw
// s_barrier. Removes the per-body full vmcnt(0) drain that __syncthreads
// emits (the m233 2-phase stall; m218 counted-vs-drain0 = +38-73%).
// Race-freedom: tile-t loads issued at body t-2, drained by vmcnt(4) at end
// of body t-1, published by that barrier; buffer overwrite at body t touches
// the set read in body t-1, whose reads were consumed before barrier t-1.
__launch_bounds__(256, 2)
__global__ void k_flash(const float* __restrict__ Q, const __bf16* __restrict__ Kb,
                        const __bf16* __restrict__ Vt, float* __restrict__ O) {
  __shared__ __align__(16) char lds[LDS_BYTES];

  const int tid = threadIdx.x;
  const int w = tid >> 6;           // wave 0..3, owns q-rows [64w, 64w+64)
  const int lane = tid & 63;
  const int quad = lane >> 4;
  const int l16 = lane & 15;

  const int bx = blockIdx.x;
  const int bh = bx & (BH - 1);
  const int q0 = (bx >> 6) * BM;

  // ---- Q fragments: fp32 load, scale, cvt to bf16, keep in regs ----
  bf16x8 qa[MT][4];
  {
    const float* qb = Q + ((size_t)bh * Ss + q0 + w * 64) * Dd;
    #pragma unroll
    for (int mt = 0; mt < MT; mt++)
      #pragma unroll
      for (int kk = 0; kk < 4; kk++) {
        const float* p = qb + (mt * 16 + l16) * Dd + kk * 32 + quad * 8;
        float4 a = ((const float4*)p)[0];
        float4 b = ((const float4*)p)[1];
        bf16x8 f;
        f[0] = f2bf(a.x * SCALE); f[1] = f2bf(a.y * SCALE);
        f[2] = f2bf(a.z * SCALE); f[3] = f2bf(a.w * SCALE);
        f[4] = f2bf(b.x * SCALE); f[5] = f2bf(b.y * SCALE);
        f[6] = f2bf(b.z * SCALE); f[7] = f2bf(b.w * SCALE);
        qa[mt][kk] = f;
      }
  }

  f32x4 acc[MT][8];
  #pragma unroll
  for (int mt = 0; mt < MT; mt++)
    #pragma unroll
    for (int dt = 0; dt < 8; dt++)
      acc[mt][dt] = (f32x4){0.f, 0.f, 0.f, 0.f};

  float lacc[MT] = {0.f, 0.f, 0.f, 0.f};

  const __bf16* kbh = Kb + (size_t)bh * Ss * Dd;   // [s][d]
  const __bf16* vbh = Vt + (size_t)bh * Ss * Dd;   // [d][s]

  // ---- per-wave stage assignment: waves 0,1 -> K frags; waves 2,3 -> V frags ----
  // lo[] = offset WITHIN a buffer set: K frag fk at fk*1024, V frag dt at TILE_B + dt*1024
  const char* gp[4];
  unsigned lo[4];
  int ginc;
  if (w < 2) {
    // K frag (kk,nt): LDS row l16 holds actual key 8*(l16>>2) + 4*nt + (l16&3)
    #pragma unroll
    for (int i = 0; i < 4; i++) {
      const int fk = w * 4 + i, kk = fk >> 1, nt = fk & 1;
      const int key = 8 * (l16 >> 2) + 4 * nt + (l16 & 3);
      gp[i] = (const char*)(kbh + (size_t)key * Dd + kk * 32 + quad * 8);
      lo[i] = (unsigned)(fk * 1024 + lane * 16);
    }
    ginc = BN * Dd * 2;             // next K tile: +32 keys
  } else {
    #pragma unroll
    for (int i = 0; i < 4; i++) {
      const int dt = (w - 2) * 4 + i;
      gp[i] = (const char*)(vbh + (size_t)(dt * 16 + l16) * Ss + quad * 8);
      lo[i] = (unsigned)(TILE_B + dt * 1024 + lane * 16);
    }
    ginc = BN * 2;                  // next V tile: +32 columns
  }

  // ---- prologue: stage tile 0 -> set 0, tile 1 -> set 1 ----
  #pragma unroll
  for (int i = 0; i < 4; i++) { gload_lds16(gp[i], lds + lo[i]); gp[i] += ginc; }
  #pragma unroll
  for (int i = 0; i < 4; i++) { gload_lds16(gp[i], lds + lo[i] + SET_B); gp[i] += ginc; }
  asm volatile("s_waitcnt vmcnt(4)" ::: "memory");   // tile 0 landed; tile 1 in flight
  __builtin_amdgcn_s_barrier();

  unsigned cbase = 0;               // compute set base; stage set = cbase + 2*SET_B (mod)
  for (int t = 0; t < NTIL; t++) {
    // ---- stage tile t+2 into the third set ----
    if (t < NTIL - 2) {
      unsigned sbase = cbase + 2 * SET_B;
      if (sbase >= (unsigned)LDS_BYTES) sbase -= (unsigned)LDS_BYTES;
      #pragma unroll
      for (int i = 0; i < 4; i++) { gload_lds16(gp[i], lds + lo[i] + sbase); gp[i] += ginc; }
    }
    const char* bK = lds + cbase;
    const char* bV = lds + cbase + TILE_B;

    // ---- S^T = K Q^T (permuted keys) -> exp2 -> pack to registers ----
    unsigned pp[MT][4];              // packed bf16 pairs: [nt*2 + half]
    #pragma unroll
    for (int nt = 0; nt < 2; nt++) {
      f32x4 sc[MT];
      #pragma unroll
      for (int mt = 0; mt < MT; mt++) sc[mt] = (f32x4){0.f, 0.f, 0.f, 0.f};
      __builtin_amdgcn_s_setprio(1);
      #pragma unroll
      for (int kk = 0; kk < 4; kk++) {
        bf16x8 bk = *(const bf16x8*)(bK + (kk * 2 + nt) * 1024 + lane * 16);
        #pragma unroll
        for (int mt = 0; mt < MT; mt++)
          sc[mt] = __builtin_amdgcn_mfma_f32_16x16x32_bf16(bk, qa[mt][kk], sc[mt], 0, 0, 0);
      }
      __builtin_amdgcn_s_setprio(0);
      #pragma unroll
      for (int mt = 0; mt < MT; mt++) {
        float p0 = exp2_hw(sc[mt][0]);
        float p1 = exp2_hw(sc[mt][1]);
        float p2 = exp2_hw(sc[mt][2]);
        float p3 = exp2_hw(sc[mt][3]);
        lacc[mt] += (p0 + p1) + (p2 + p3);
        pp[mt][nt * 2 + 0] = pk2(p0, p1);
        pp[mt][nt * 2 + 1] = pk2(p2, p3);
      }
    }

    // ---- O += P V entirely from registers (A = pa, B = V^T frag) ----
    bf16x8 pa[MT];
    #pragma unroll
    for (int mt = 0; mt < MT; mt++) {
      uint4 u4 = make_uint4(pp[mt][0], pp[mt][1], pp[mt][2], pp[mt][3]);
      pa[mt] = __builtin_bit_cast(bf16x8, u4);
    }
    __builtin_amdgcn_s_setprio(1);
    #pragma unroll
    for (int dt = 0; dt < 8; dt++) {
      bf16x8 bv = *(const bf16x8*)(bV + dt * 1024 + lane * 16);
      #pragma unroll
      for (int mt = 0; mt < MT; mt++)
        acc[mt][dt] = __builtin_amdgcn_mfma_f32_16x16x32_bf16(pa[mt], bv, acc[mt][dt], 0, 0, 0);
    }
    __builtin_amdgcn_s_setprio(0);

    // ---- counted-vmcnt barrier: drain tile t+1's loads only ----
    if (t < NTIL - 1) {
      if (t < NTIL - 2) asm volatile("s_waitcnt vmcnt(4)" ::: "memory");
      else              asm volatile("s_waitcnt vmcnt(0)" ::: "memory");
      __builtin_amdgcn_s_barrier();
    }
    cbase += SET_B;
    if (cbase >= (unsigned)LDS_BYTES) cbase = 0;
  }

  // ---- final l reduction: sum quads, broadcast to C-layout rows ----
  float inv_l[MT][4];
  #pragma unroll
  for (int mt = 0; mt < MT; mt++) {
    float l = lacc[mt];
    l += __shfl_xor(l, 16);
    l += __shfl_xor(l, 32);
    #pragma unroll
    for (int r = 0; r < 4; r++) {
      float lr = __shfl(l, (lane & 48) | (quad * 4 + r));
      inv_l[mt][r] = 1.0f / lr;
    }
  }

  // ---- epilogue: O / l ----
  float* ob = O + ((size_t)bh * Ss + q0 + w * 64) * Dd;
  #pragma unroll
  for (int mt = 0; mt < MT; mt++)
    #pragma unroll
    for (int r = 0; r < 4; r++) {
      const float inv = inv_l[mt][r];
      const int row = mt * 16 + quad * 4 + r;
      #pragma unroll
      for (int dt = 0; dt < 8; dt++)
        ob[row * Dd + dt * 16 + l16] = acc[mt][dt][r] * inv;
    }
}

extern "C" void kernel_launch(void* const* d_in, const int* in_sizes, int n_in,
                              void* d_out, int out_size, void* d_ws, size_t ws_size,
                              hipStream_t stream) {
  const float* Q = (const float*)d_in[0];
  const float* K = (const float*)d_in[1];
  const float* V = (const float*)d_in[2];
  float* O = (float*)d_out;
  const size_t elems = (size_t)BH * Ss * Dd;   // 16,777,216
  __bf16* Kb = (__bf16*)d_ws;
  __bf16* Vt = Kb + elems;

  k_prep<<<4096, 256, 0, stream>>>(K, Kb, V, Vt);
  k_flash<<<dim3((Ss / BM) * BH), 256, 0, stream>>>(Q, Kb, Vt, O);
}